// Round 9
// baseline (267.637 us; speedup 1.0000x reference)
//
#include <hip/hip_runtime.h>
#include <string.h>

#define HIDDEN 128
#define LEAKY 0.01f
#define SCAN_CHUNK 1024  // 256 threads * 4 elems

// ---------------- helpers ----------------------------------------------------
__device__ __forceinline__ unsigned int rne_bf16(float f) {
    unsigned int x = __float_as_uint(f);
    return (x + 0x7FFFu + ((x >> 16) & 1u)) >> 16;
}

// ---------------- Stage 1+2 fused: scores + bf16 cvt (blocks [0,SB)) ---------
//                                   histogram      (blocks [SB, SB+HB))
// The scores half is HBM-BW-bound, the hist half is atomic-latency-bound;
// running them concurrently hides the hist behind the scores' BW usage.
__global__ void scores_hist_k(const float* __restrict__ x,
                              const float* __restrict__ w_i,
                              const float* __restrict__ w_j,
                              float* __restrict__ s_i,
                              float* __restrict__ s_j,
                              unsigned short* __restrict__ xb,
                              const int* __restrict__ h,
                              int* __restrict__ counts,
                              int n_nodes, int n_edges, int score_blocks) {
    if ((int)blockIdx.x < score_blocks) {
        int gtid = blockIdx.x * blockDim.x + threadIdx.x;
        int node = gtid >> 6;
        int lane = threadIdx.x & 63;
        if (node >= n_nodes) return;
        const float2* xr = reinterpret_cast<const float2*>(x + (size_t)node * HIDDEN);
        float2 xv = xr[lane];
        unsigned int pk = rne_bf16(xv.x) | (rne_bf16(xv.y) << 16);
        reinterpret_cast<unsigned int*>(xb + (size_t)node * HIDDEN)[lane] = pk;
        float2 wi = reinterpret_cast<const float2*>(w_i)[lane];
        float2 wj = reinterpret_cast<const float2*>(w_j)[lane];
        float di = xv.x * wi.x + xv.y * wi.y;
        float dj = xv.x * wj.x + xv.y * wj.y;
        #pragma unroll
        for (int off = 32; off > 0; off >>= 1) {
            di += __shfl_xor(di, off, 64);
            dj += __shfl_xor(dj, off, 64);
        }
        if (lane == 0) {
            s_i[node] = di;
            s_j[node] = dj;
        }
    } else {
        int b = blockIdx.x - score_blocks;
        int i = (b * blockDim.x + threadIdx.x) * 4;
        if (i + 4 <= n_edges) {
            int4 hv = *reinterpret_cast<const int4*>(h + i);
            atomicAdd(&counts[hv.x], 1);
            atomicAdd(&counts[hv.y], 1);
            atomicAdd(&counts[hv.z], 1);
            atomicAdd(&counts[hv.w], 1);
        } else {
            for (; i < n_edges; ++i) atomicAdd(&counts[h[i]], 1);
        }
    }
}

// ---- fallback separate kernels (no-bf16 path only) --------------------------
__global__ void node_scores_k(const float* __restrict__ x,
                              const float* __restrict__ w_i,
                              const float* __restrict__ w_j,
                              float* __restrict__ s_i,
                              float* __restrict__ s_j,
                              int n_nodes) {
    int gtid = blockIdx.x * blockDim.x + threadIdx.x;
    int node = gtid >> 6;
    int lane = threadIdx.x & 63;
    if (node >= n_nodes) return;
    const float2* xr = reinterpret_cast<const float2*>(x + (size_t)node * HIDDEN);
    float2 xv = xr[lane];
    float2 wi = reinterpret_cast<const float2*>(w_i)[lane];
    float2 wj = reinterpret_cast<const float2*>(w_j)[lane];
    float di = xv.x * wi.x + xv.y * wi.y;
    float dj = xv.x * wj.x + xv.y * wj.y;
    #pragma unroll
    for (int off = 32; off > 0; off >>= 1) {
        di += __shfl_xor(di, off, 64);
        dj += __shfl_xor(dj, off, 64);
    }
    if (lane == 0) {
        s_i[node] = di;
        s_j[node] = dj;
    }
}

__global__ void hist_k(const int* __restrict__ h, int* __restrict__ counts,
                       int n_edges) {
    int i = (blockIdx.x * blockDim.x + threadIdx.x) * 4;
    if (i + 4 <= n_edges) {
        int4 hv = *reinterpret_cast<const int4*>(h + i);
        atomicAdd(&counts[hv.x], 1);
        atomicAdd(&counts[hv.y], 1);
        atomicAdd(&counts[hv.z], 1);
        atomicAdd(&counts[hv.w], 1);
    } else {
        for (; i < n_edges; ++i) atomicAdd(&counts[h[i]], 1);
    }
}

// ---------------- Stage 3: exclusive scan of counts -> offsets ---------------
__global__ void scan1_k(const int* __restrict__ counts, int* __restrict__ offsets,
                        int* __restrict__ blockSums, int n) {
    __shared__ int lds[256];
    int tid = threadIdx.x;
    int base = blockIdx.x * SCAN_CHUNK + tid * 4;
    int v0 = (base + 0 < n) ? counts[base + 0] : 0;
    int v1 = (base + 1 < n) ? counts[base + 1] : 0;
    int v2 = (base + 2 < n) ? counts[base + 2] : 0;
    int v3 = (base + 3 < n) ? counts[base + 3] : 0;
    int tsum = v0 + v1 + v2 + v3;
    lds[tid] = tsum;
    __syncthreads();
    for (int off = 1; off < 256; off <<= 1) {
        int addend = (tid >= off) ? lds[tid - off] : 0;
        __syncthreads();
        if (tid >= off) lds[tid] += addend;
        __syncthreads();
    }
    int incl = lds[tid];
    int excl = incl - tsum;
    if (tid == 255) blockSums[blockIdx.x] = incl;
    int run = excl;
    if (base + 0 < n) { offsets[base + 0] = run; } run += v0;
    if (base + 1 < n) { offsets[base + 1] = run; } run += v1;
    if (base + 2 < n) { offsets[base + 2] = run; } run += v2;
    if (base + 3 < n) { offsets[base + 3] = run; }
}

__global__ void scan2_k(int* __restrict__ blockSums, int nblocks) {
    __shared__ int lds[256];
    int tid = threadIdx.x;
    int v = (tid < nblocks) ? blockSums[tid] : 0;
    lds[tid] = v;
    __syncthreads();
    for (int off = 1; off < 256; off <<= 1) {
        int addend = (tid >= off) ? lds[tid - off] : 0;
        __syncthreads();
        if (tid >= off) lds[tid] += addend;
        __syncthreads();
    }
    if (tid < nblocks) blockSums[tid] = lds[tid] - v;  // exclusive
}

__global__ void scan3_k(int* __restrict__ offsets, const int* __restrict__ blockSums,
                        int n) {
    int base = blockIdx.x * SCAN_CHUNK + threadIdx.x * 4;
    int add = blockSums[blockIdx.x];
    if (base + 0 < n) offsets[base + 0] += add;
    if (base + 1 < n) offsets[base + 1] += add;
    if (base + 2 < n) offsets[base + 2] += add;
    if (base + 3 < n) offsets[base + 3] += add;
}

// ---------------- Stage 4: scatter edges into CSR order ----------------------
// 4 edges / thread (round-7 thread count -> ~40% occupancy), fully inline and
// phase-batched (round-8 concurrency): 4 independent score gathers + exp,
// then 4 back-to-back atomics, then 4 stores. exp ONCE per edge. offsets[]
// doubles as allocation cursor (aggregate reconstructs beg = off - count).
__global__ void scatter_k(const float* __restrict__ s_i,
                          const float* __restrict__ s_j,
                          const int* __restrict__ h,
                          const int* __restrict__ t,
                          int* __restrict__ offsets,
                          int2* __restrict__ te_sorted,
                          int n_edges) {
    int base = (blockIdx.x * blockDim.x + threadIdx.x) * 4;
    if (base + 4 <= n_edges) {
        int4 hv = *reinterpret_cast<const int4*>(h + base);
        int4 tv = *reinterpret_cast<const int4*>(t + base);
        int hh[4] = {hv.x, hv.y, hv.z, hv.w};
        int tt[4] = {tv.x, tv.y, tv.z, tv.w};
        float ex[4];
        int pos[4];
        #pragma unroll
        for (int k = 0; k < 4; ++k) {
            float e = s_i[hh[k]] + s_j[tt[k]];
            e = e > 0.0f ? e : LEAKY * e;
            ex[k] = __expf(e);   // softmax shift-invariant; e is O(+-10)
        }
        #pragma unroll
        for (int k = 0; k < 4; ++k)
            pos[k] = atomicAdd(&offsets[hh[k]], 1);
        #pragma unroll
        for (int k = 0; k < 4; ++k) {
            int2 te;
            te.x = tt[k];
            te.y = __float_as_int(ex[k]);
            te_sorted[pos[k]] = te;
        }
    } else {
        for (int i = base; i < n_edges; ++i) {
            int hh = h[i];
            int tt = t[i];
            float e = s_i[hh] + s_j[tt];
            e = e > 0.0f ? e : LEAKY * e;
            float ex = __expf(e);
            int pos = atomicAdd(&offsets[hh], 1);
            int2 te;
            te.x = tt;
            te.y = __float_as_int(ex);
            te_sorted[pos] = te;
        }
    }
}

// ---------------- Stage 5: single-pass aggregation, fused ReLU ---------------
// One wave per node; bf16 row gathers (256B). readfirstlane(node) -> wave-
// uniform metadata/edge-stream addresses -> scalar s_load. Main loop:
// unpredicated unroll-8; tail: ONE predicated 8-wide block.
__global__ void aggregate_bf16_k(const unsigned short* __restrict__ xb,
                                 const int* __restrict__ offsets,
                                 const int* __restrict__ counts,
                                 const long long* __restrict__ te_sorted,
                                 float* __restrict__ out,
                                 int n_nodes) {
    int gtid = blockIdx.x * blockDim.x + threadIdx.x;
    int node = __builtin_amdgcn_readfirstlane(gtid >> 6);  // wave-uniform
    int lane = threadIdx.x & 63;
    if (node >= n_nodes) return;
    long long* dst = reinterpret_cast<long long*>(out + (size_t)node * HIDDEN) + lane;
    int end = offsets[node];           // post-scatter: beg + deg (s_load)
    int deg = counts[node];            // s_load
    if (deg <= 0) {                    // must still write out (harness poisons)
        __builtin_nontemporal_store(0LL, dst);
        return;
    }
    int beg = end - deg;
    float accx = 0.0f, accy = 0.0f, ssum = 0.0f;
    int j = beg;
    int main_end = beg + (deg & ~7);
    for (; j < main_end; j += 8) {     // unpredicated main loop
        long long te[8];
        unsigned int u[8];
        #pragma unroll
        for (int k = 0; k < 8; ++k) te[k] = te_sorted[j + k];   // scalar loads
        #pragma unroll
        for (int k = 0; k < 8; ++k)
            u[k] = *reinterpret_cast<const unsigned int*>(
                xb + (size_t)(int)te[k] * HIDDEN + 2 * lane);
        #pragma unroll
        for (int k = 0; k < 8; ++k) {
            float a = __int_as_float((int)(te[k] >> 32));
            float fx = __uint_as_float(u[k] << 16);
            float fy = __uint_as_float(u[k] & 0xFFFF0000u);
            ssum += a;
            accx += a * fx;
            accy += a * fy;
        }
    }
    if (j < end) {                     // single predicated tail block
        long long te[8];
        unsigned int u[8];
        #pragma unroll
        for (int k = 0; k < 8; ++k) {
            int jj = j + k;
            int jc = jj < end ? jj : end - 1;   // clamp: dup loads hit cache
            te[k] = te_sorted[jc];
        }
        #pragma unroll
        for (int k = 0; k < 8; ++k)
            u[k] = *reinterpret_cast<const unsigned int*>(
                xb + (size_t)(int)te[k] * HIDDEN + 2 * lane);
        #pragma unroll
        for (int k = 0; k < 8; ++k) {
            float a = __int_as_float((int)(te[k] >> 32));
            a = (j + k < end) ? a : 0.0f;       // zero padding slots
            float fx = __uint_as_float(u[k] << 16);
            float fy = __uint_as_float(u[k] & 0xFFFF0000u);
            ssum += a;
            accx += a * fx;
            accy += a * fy;
        }
    }
    float inv = 1.0f / ssum;
    float ox = accx * inv, oy = accy * inv;
    float2 o;
    o.x = ox > 0.0f ? ox : 0.0f;   // fused ReLU
    o.y = oy > 0.0f ? oy : 0.0f;
    long long bits;
    memcpy(&bits, &o, 8);
    __builtin_nontemporal_store(bits, dst);     // don't evict x from L2/L3
}

// fp32 fallback (only if ws can't hold the bf16 copy).
__global__ void aggregate_f32_k(const float* __restrict__ x,
                                const int* __restrict__ offsets,
                                const int* __restrict__ counts,
                                const int2* __restrict__ te_sorted,
                                float* __restrict__ out,
                                int n_nodes) {
    int gtid = blockIdx.x * blockDim.x + threadIdx.x;
    int node = __builtin_amdgcn_readfirstlane(gtid >> 6);
    int lane = threadIdx.x & 63;
    if (node >= n_nodes) return;
    long long* dst = reinterpret_cast<long long*>(out + (size_t)node * HIDDEN) + lane;
    int end = offsets[node];
    int deg = counts[node];
    if (deg <= 0) {
        __builtin_nontemporal_store(0LL, dst);
        return;
    }
    int beg = end - deg;
    float accx = 0.0f, accy = 0.0f, ssum = 0.0f;
    for (int j = beg; j < end; j += 8) {
        int2 te[8];
        float2 v[8];
        #pragma unroll
        for (int k = 0; k < 8; ++k) {
            int jj = j + k;
            int jc = jj < end ? jj : end - 1;
            te[k] = te_sorted[jc];
        }
        #pragma unroll
        for (int k = 0; k < 8; ++k)
            v[k] = reinterpret_cast<const float2*>(
                x + (size_t)te[k].x * HIDDEN)[lane];
        #pragma unroll
        for (int k = 0; k < 8; ++k) {
            float a = __int_as_float(te[k].y);
            a = (j + k < end) ? a : 0.0f;
            ssum += a;
            accx += a * v[k].x;
            accy += a * v[k].y;
        }
    }
    float inv = 1.0f / ssum;
    float ox = accx * inv, oy = accy * inv;
    float2 o;
    o.x = ox > 0.0f ? ox : 0.0f;
    o.y = oy > 0.0f ? oy : 0.0f;
    long long bits;
    memcpy(&bits, &o, 8);
    __builtin_nontemporal_store(bits, dst);
}

extern "C" void kernel_launch(void* const* d_in, const int* in_sizes, int n_in,
                              void* d_out, int out_size, void* d_ws, size_t ws_size,
                              hipStream_t stream) {
    const float* x   = (const float*)d_in[0];
    const float* w_i = (const float*)d_in[1];
    const float* w_j = (const float*)d_in[2];
    const int*   h   = (const int*)d_in[3];
    const int*   t   = (const int*)d_in[4];
    float* out = (float*)d_out;

    const int n_nodes = in_sizes[0] / HIDDEN;
    const int n_edges = in_sizes[3];
    const long long n_x = (long long)n_nodes * HIDDEN;
    const int nchunks = (n_nodes + SCAN_CHUNK - 1) / SCAN_CHUNK;  // <= 256

    // Workspace layout:
    // s_i[N] f | s_j[N] f | counts[N] i | offsets[N] i | blockSums[256] i |
    // te_sorted[E] int2 | x_bf16[N*128] u16
    float* s_i       = (float*)d_ws;
    float* s_j       = s_i + n_nodes;
    int*   counts    = (int*)(s_j + n_nodes);
    int*   offsets   = counts + n_nodes;
    int*   blockSums = offsets + n_nodes;
    int2*  te_sorted = reinterpret_cast<int2*>(blockSums + 256);
    unsigned short* x_bf16 = reinterpret_cast<unsigned short*>(te_sorted + n_edges);

    size_t need_bf16 = (size_t)((char*)(x_bf16 + n_x) - (char*)d_ws);
    const bool use_bf16 = ws_size >= need_bf16;

    hipMemsetAsync(counts, 0, (size_t)n_nodes * sizeof(int), stream);

    {   // Stage 1+2: scores/cvt (BW-bound) + hist (atomic-bound), concurrent.
        int score_blocks = (n_nodes * 64 + 255) / 256;
        int hist_blocks  = (n_edges + 1023) / 1024;
        if (use_bf16) {
            scores_hist_k<<<score_blocks + hist_blocks, 256, 0, stream>>>(
                x, w_i, w_j, s_i, s_j, x_bf16, h, counts,
                n_nodes, n_edges, score_blocks);
        } else {
            node_scores_k<<<score_blocks, 256, 0, stream>>>(x, w_i, w_j,
                                                            s_i, s_j, n_nodes);
            hist_k<<<hist_blocks, 256, 0, stream>>>(h, counts, n_edges);
        }
    }
    {   // Stage 3: exclusive scan counts -> offsets.
        scan1_k<<<nchunks, 256, 0, stream>>>(counts, offsets, blockSums, n_nodes);
        scan2_k<<<1, 256, 0, stream>>>(blockSums, nchunks);
        scan3_k<<<nchunks, 256, 0, stream>>>(offsets, blockSums, n_nodes);
    }
    {   // Stage 4: scatter into CSR order (4 edges/thread, batched atomics).
        int blocks = (n_edges / 4 + 255) / 256 + 1;
        scatter_k<<<blocks, 256, 0, stream>>>(s_i, s_j, h, t, offsets,
                                              te_sorted, n_edges);
    }
    {   // Stage 5: aggregate + ReLU, wave per node.
        int blocks = (n_nodes * 64 + 255) / 256;
        if (use_bf16)
            aggregate_bf16_k<<<blocks, 256, 0, stream>>>(
                x_bf16, offsets, counts,
                reinterpret_cast<const long long*>(te_sorted), out, n_nodes);
        else
            aggregate_f32_k<<<blocks, 256, 0, stream>>>(
                x, offsets, counts, te_sorted, out, n_nodes);
    }
}

// Round 10
// 231.055 us; speedup vs baseline: 1.1583x; 1.1583x over previous
//
#include <hip/hip_runtime.h>
#include <string.h>

#define HIDDEN 128
#define LEAKY 0.01f
#define SCAN_CHUNK 1024  // 256 threads * 4 elems

// ---------------- helpers ----------------------------------------------------
__device__ __forceinline__ unsigned int rne_bf16(float f) {
    unsigned int x = __float_as_uint(f);
    return (x + 0x7FFFu + ((x >> 16) & 1u)) >> 16;
}

// ---------------- Stage 1+2 fused: scores + bf16 cvt (blocks [0,SB)) ---------
//                                   histogram      (blocks [SB, SB+HB))
// The scores half is HBM-BW-bound, the hist half is atomic-latency-bound;
// running them concurrently hides the hist behind the scores' BW usage.
__global__ void scores_hist_k(const float* __restrict__ x,
                              const float* __restrict__ w_i,
                              const float* __restrict__ w_j,
                              float* __restrict__ s_i,
                              float* __restrict__ s_j,
                              unsigned short* __restrict__ xb,
                              const int* __restrict__ h,
                              int* __restrict__ counts,
                              int n_nodes, int n_edges, int score_blocks) {
    if ((int)blockIdx.x < score_blocks) {
        int gtid = blockIdx.x * blockDim.x + threadIdx.x;
        int node = gtid >> 6;
        int lane = threadIdx.x & 63;
        if (node >= n_nodes) return;
        const float2* xr = reinterpret_cast<const float2*>(x + (size_t)node * HIDDEN);
        float2 xv = xr[lane];
        unsigned int pk = rne_bf16(xv.x) | (rne_bf16(xv.y) << 16);
        reinterpret_cast<unsigned int*>(xb + (size_t)node * HIDDEN)[lane] = pk;
        float2 wi = reinterpret_cast<const float2*>(w_i)[lane];
        float2 wj = reinterpret_cast<const float2*>(w_j)[lane];
        float di = xv.x * wi.x + xv.y * wi.y;
        float dj = xv.x * wj.x + xv.y * wj.y;
        #pragma unroll
        for (int off = 32; off > 0; off >>= 1) {
            di += __shfl_xor(di, off, 64);
            dj += __shfl_xor(dj, off, 64);
        }
        if (lane == 0) {
            s_i[node] = di;
            s_j[node] = dj;
        }
    } else {
        int b = blockIdx.x - score_blocks;
        int i = (b * blockDim.x + threadIdx.x) * 4;
        if (i + 4 <= n_edges) {
            int4 hv = *reinterpret_cast<const int4*>(h + i);
            atomicAdd(&counts[hv.x], 1);
            atomicAdd(&counts[hv.y], 1);
            atomicAdd(&counts[hv.z], 1);
            atomicAdd(&counts[hv.w], 1);
        } else {
            for (; i < n_edges; ++i) atomicAdd(&counts[h[i]], 1);
        }
    }
}

// ---- fallback separate kernels (no-bf16 path only) --------------------------
__global__ void node_scores_k(const float* __restrict__ x,
                              const float* __restrict__ w_i,
                              const float* __restrict__ w_j,
                              float* __restrict__ s_i,
                              float* __restrict__ s_j,
                              int n_nodes) {
    int gtid = blockIdx.x * blockDim.x + threadIdx.x;
    int node = gtid >> 6;
    int lane = threadIdx.x & 63;
    if (node >= n_nodes) return;
    const float2* xr = reinterpret_cast<const float2*>(x + (size_t)node * HIDDEN);
    float2 xv = xr[lane];
    float2 wi = reinterpret_cast<const float2*>(w_i)[lane];
    float2 wj = reinterpret_cast<const float2*>(w_j)[lane];
    float di = xv.x * wi.x + xv.y * wi.y;
    float dj = xv.x * wj.x + xv.y * wj.y;
    #pragma unroll
    for (int off = 32; off > 0; off >>= 1) {
        di += __shfl_xor(di, off, 64);
        dj += __shfl_xor(dj, off, 64);
    }
    if (lane == 0) {
        s_i[node] = di;
        s_j[node] = dj;
    }
}

__global__ void hist_k(const int* __restrict__ h, int* __restrict__ counts,
                       int n_edges) {
    int i = (blockIdx.x * blockDim.x + threadIdx.x) * 4;
    if (i + 4 <= n_edges) {
        int4 hv = *reinterpret_cast<const int4*>(h + i);
        atomicAdd(&counts[hv.x], 1);
        atomicAdd(&counts[hv.y], 1);
        atomicAdd(&counts[hv.z], 1);
        atomicAdd(&counts[hv.w], 1);
    } else {
        for (; i < n_edges; ++i) atomicAdd(&counts[h[i]], 1);
    }
}

// ---------------- Stage 3: exclusive scan of counts -> offsets ---------------
__global__ void scan1_k(const int* __restrict__ counts, int* __restrict__ offsets,
                        int* __restrict__ blockSums, int n) {
    __shared__ int lds[256];
    int tid = threadIdx.x;
    int base = blockIdx.x * SCAN_CHUNK + tid * 4;
    int v0 = (base + 0 < n) ? counts[base + 0] : 0;
    int v1 = (base + 1 < n) ? counts[base + 1] : 0;
    int v2 = (base + 2 < n) ? counts[base + 2] : 0;
    int v3 = (base + 3 < n) ? counts[base + 3] : 0;
    int tsum = v0 + v1 + v2 + v3;
    lds[tid] = tsum;
    __syncthreads();
    for (int off = 1; off < 256; off <<= 1) {
        int addend = (tid >= off) ? lds[tid - off] : 0;
        __syncthreads();
        if (tid >= off) lds[tid] += addend;
        __syncthreads();
    }
    int incl = lds[tid];
    int excl = incl - tsum;
    if (tid == 255) blockSums[blockIdx.x] = incl;
    int run = excl;
    if (base + 0 < n) { offsets[base + 0] = run; } run += v0;
    if (base + 1 < n) { offsets[base + 1] = run; } run += v1;
    if (base + 2 < n) { offsets[base + 2] = run; } run += v2;
    if (base + 3 < n) { offsets[base + 3] = run; }
}

__global__ void scan2_k(int* __restrict__ blockSums, int nblocks) {
    __shared__ int lds[256];
    int tid = threadIdx.x;
    int v = (tid < nblocks) ? blockSums[tid] : 0;
    lds[tid] = v;
    __syncthreads();
    for (int off = 1; off < 256; off <<= 1) {
        int addend = (tid >= off) ? lds[tid - off] : 0;
        __syncthreads();
        if (tid >= off) lds[tid] += addend;
        __syncthreads();
    }
    if (tid < nblocks) blockSums[tid] = lds[tid] - v;  // exclusive
}

__global__ void scan3_k(int* __restrict__ offsets, const int* __restrict__ blockSums,
                        int n) {
    int base = blockIdx.x * SCAN_CHUNK + threadIdx.x * 4;
    int add = blockSums[blockIdx.x];
    if (base + 0 < n) offsets[base + 0] += add;
    if (base + 1 < n) offsets[base + 1] += add;
    if (base + 2 < n) offsets[base + 2] += add;
    if (base + 3 < n) offsets[base + 3] += add;
}

// ---------------- Stage 4: scatter edges into CSR order ----------------------
// EXACT round-7 form — measured fastest (80us vs 122-127us batched).
// The non-restrict helper forces per-edge serialization (atomic -> wait ->
// store -> next), which THROTTLES per-thread random-op bursts; with ~400K
// threads the TLP covers latency, and un-throttled batching (r8/r9) congested
// the TCC/fabric instead. Do not "optimize" this into batched form again.
__device__ __forceinline__ void scatter_one(const float* s_i, const float* s_j,
                                            int hh, int tt, int* offsets,
                                            int2* te_sorted) {
    float e = s_i[hh] + s_j[tt];
    e = e > 0.0f ? e : LEAKY * e;
    float ex = __expf(e);  // softmax shift-invariant; e is O(+-10), no max pass
    int pos = atomicAdd(&offsets[hh], 1);
    int2 te;
    te.x = tt;
    te.y = __float_as_int(ex);
    te_sorted[pos] = te;
}

__global__ void scatter_k(const float* __restrict__ s_i,
                          const float* __restrict__ s_j,
                          const int* __restrict__ h,
                          const int* __restrict__ t,
                          int* __restrict__ offsets,
                          int2* __restrict__ te_sorted,
                          int n_edges) {
    int i = (blockIdx.x * blockDim.x + threadIdx.x) * 4;
    if (i + 4 <= n_edges) {
        int4 hv = *reinterpret_cast<const int4*>(h + i);
        int4 tv = *reinterpret_cast<const int4*>(t + i);
        scatter_one(s_i, s_j, hv.x, tv.x, offsets, te_sorted);
        scatter_one(s_i, s_j, hv.y, tv.y, offsets, te_sorted);
        scatter_one(s_i, s_j, hv.z, tv.z, offsets, te_sorted);
        scatter_one(s_i, s_j, hv.w, tv.w, offsets, te_sorted);
    } else {
        for (; i < n_edges; ++i)
            scatter_one(s_i, s_j, h[i], t[i], offsets, te_sorted);
    }
}

// ---------------- Stage 5: single-pass aggregation, fused ReLU ---------------
// One wave per node; bf16 row gathers (256B). readfirstlane(node) -> wave-
// uniform metadata/edge-stream addresses -> scalar s_load. Main loop:
// unpredicated unroll-8; tail: ONE predicated 8-wide block.
__global__ void aggregate_bf16_k(const unsigned short* __restrict__ xb,
                                 const int* __restrict__ offsets,
                                 const int* __restrict__ counts,
                                 const long long* __restrict__ te_sorted,
                                 float* __restrict__ out,
                                 int n_nodes) {
    int gtid = blockIdx.x * blockDim.x + threadIdx.x;
    int node = __builtin_amdgcn_readfirstlane(gtid >> 6);  // wave-uniform
    int lane = threadIdx.x & 63;
    if (node >= n_nodes) return;
    long long* dst = reinterpret_cast<long long*>(out + (size_t)node * HIDDEN) + lane;
    int end = offsets[node];           // post-scatter: beg + deg (s_load)
    int deg = counts[node];            // s_load
    if (deg <= 0) {                    // must still write out (harness poisons)
        __builtin_nontemporal_store(0LL, dst);
        return;
    }
    int beg = end - deg;
    float accx = 0.0f, accy = 0.0f, ssum = 0.0f;
    int j = beg;
    int main_end = beg + (deg & ~7);
    for (; j < main_end; j += 8) {     // unpredicated main loop
        long long te[8];
        unsigned int u[8];
        #pragma unroll
        for (int k = 0; k < 8; ++k) te[k] = te_sorted[j + k];   // scalar loads
        #pragma unroll
        for (int k = 0; k < 8; ++k)
            u[k] = *reinterpret_cast<const unsigned int*>(
                xb + (size_t)(int)te[k] * HIDDEN + 2 * lane);
        #pragma unroll
        for (int k = 0; k < 8; ++k) {
            float a = __int_as_float((int)(te[k] >> 32));
            float fx = __uint_as_float(u[k] << 16);
            float fy = __uint_as_float(u[k] & 0xFFFF0000u);
            ssum += a;
            accx += a * fx;
            accy += a * fy;
        }
    }
    if (j < end) {                     // single predicated tail block
        long long te[8];
        unsigned int u[8];
        #pragma unroll
        for (int k = 0; k < 8; ++k) {
            int jj = j + k;
            int jc = jj < end ? jj : end - 1;   // clamp: dup loads hit cache
            te[k] = te_sorted[jc];
        }
        #pragma unroll
        for (int k = 0; k < 8; ++k)
            u[k] = *reinterpret_cast<const unsigned int*>(
                xb + (size_t)(int)te[k] * HIDDEN + 2 * lane);
        #pragma unroll
        for (int k = 0; k < 8; ++k) {
            float a = __int_as_float((int)(te[k] >> 32));
            a = (j + k < end) ? a : 0.0f;       // zero padding slots
            float fx = __uint_as_float(u[k] << 16);
            float fy = __uint_as_float(u[k] & 0xFFFF0000u);
            ssum += a;
            accx += a * fx;
            accy += a * fy;
        }
    }
    float inv = 1.0f / ssum;
    float ox = accx * inv, oy = accy * inv;
    float2 o;
    o.x = ox > 0.0f ? ox : 0.0f;   // fused ReLU
    o.y = oy > 0.0f ? oy : 0.0f;
    long long bits;
    memcpy(&bits, &o, 8);
    __builtin_nontemporal_store(bits, dst);     // don't evict x from L2/L3
}

// fp32 fallback (only if ws can't hold the bf16 copy).
__global__ void aggregate_f32_k(const float* __restrict__ x,
                                const int* __restrict__ offsets,
                                const int* __restrict__ counts,
                                const int2* __restrict__ te_sorted,
                                float* __restrict__ out,
                                int n_nodes) {
    int gtid = blockIdx.x * blockDim.x + threadIdx.x;
    int node = __builtin_amdgcn_readfirstlane(gtid >> 6);
    int lane = threadIdx.x & 63;
    if (node >= n_nodes) return;
    long long* dst = reinterpret_cast<long long*>(out + (size_t)node * HIDDEN) + lane;
    int end = offsets[node];
    int deg = counts[node];
    if (deg <= 0) {
        __builtin_nontemporal_store(0LL, dst);
        return;
    }
    int beg = end - deg;
    float accx = 0.0f, accy = 0.0f, ssum = 0.0f;
    for (int j = beg; j < end; j += 8) {
        int2 te[8];
        float2 v[8];
        #pragma unroll
        for (int k = 0; k < 8; ++k) {
            int jj = j + k;
            int jc = jj < end ? jj : end - 1;
            te[k] = te_sorted[jc];
        }
        #pragma unroll
        for (int k = 0; k < 8; ++k)
            v[k] = reinterpret_cast<const float2*>(
                x + (size_t)te[k].x * HIDDEN)[lane];
        #pragma unroll
        for (int k = 0; k < 8; ++k) {
            float a = __int_as_float(te[k].y);
            a = (j + k < end) ? a : 0.0f;
            ssum += a;
            accx += a * v[k].x;
            accy += a * v[k].y;
        }
    }
    float inv = 1.0f / ssum;
    float ox = accx * inv, oy = accy * inv;
    float2 o;
    o.x = ox > 0.0f ? ox : 0.0f;
    o.y = oy > 0.0f ? oy : 0.0f;
    long long bits;
    memcpy(&bits, &o, 8);
    __builtin_nontemporal_store(bits, dst);
}

extern "C" void kernel_launch(void* const* d_in, const int* in_sizes, int n_in,
                              void* d_out, int out_size, void* d_ws, size_t ws_size,
                              hipStream_t stream) {
    const float* x   = (const float*)d_in[0];
    const float* w_i = (const float*)d_in[1];
    const float* w_j = (const float*)d_in[2];
    const int*   h   = (const int*)d_in[3];
    const int*   t   = (const int*)d_in[4];
    float* out = (float*)d_out;

    const int n_nodes = in_sizes[0] / HIDDEN;
    const int n_edges = in_sizes[3];
    const long long n_x = (long long)n_nodes * HIDDEN;
    const int nchunks = (n_nodes + SCAN_CHUNK - 1) / SCAN_CHUNK;  // <= 256

    // Workspace layout:
    // s_i[N] f | s_j[N] f | counts[N] i | offsets[N] i | blockSums[256] i |
    // te_sorted[E] int2 | x_bf16[N*128] u16
    float* s_i       = (float*)d_ws;
    float* s_j       = s_i + n_nodes;
    int*   counts    = (int*)(s_j + n_nodes);
    int*   offsets   = counts + n_nodes;
    int*   blockSums = offsets + n_nodes;
    int2*  te_sorted = reinterpret_cast<int2*>(blockSums + 256);
    unsigned short* x_bf16 = reinterpret_cast<unsigned short*>(te_sorted + n_edges);

    size_t need_bf16 = (size_t)((char*)(x_bf16 + n_x) - (char*)d_ws);
    const bool use_bf16 = ws_size >= need_bf16;

    hipMemsetAsync(counts, 0, (size_t)n_nodes * sizeof(int), stream);

    {   // Stage 1+2: scores/cvt (BW-bound) + hist (atomic-bound), concurrent.
        int score_blocks = (n_nodes * 64 + 255) / 256;
        int hist_blocks  = (n_edges + 1023) / 1024;
        if (use_bf16) {
            scores_hist_k<<<score_blocks + hist_blocks, 256, 0, stream>>>(
                x, w_i, w_j, s_i, s_j, x_bf16, h, counts,
                n_nodes, n_edges, score_blocks);
        } else {
            node_scores_k<<<score_blocks, 256, 0, stream>>>(x, w_i, w_j,
                                                            s_i, s_j, n_nodes);
            hist_k<<<hist_blocks, 256, 0, stream>>>(h, counts, n_edges);
        }
    }
    {   // Stage 3: exclusive scan counts -> offsets.
        scan1_k<<<nchunks, 256, 0, stream>>>(counts, offsets, blockSums, n_nodes);
        scan2_k<<<1, 256, 0, stream>>>(blockSums, nchunks);
        scan3_k<<<nchunks, 256, 0, stream>>>(offsets, blockSums, n_nodes);
    }
    {   // Stage 4: scatter into CSR order (round-7 serialized form — fastest).
        int blocks = (n_edges / 4 + 255) / 256 + 1;
        scatter_k<<<blocks, 256, 0, stream>>>(s_i, s_j, h, t, offsets,
                                              te_sorted, n_edges);
    }
    {   // Stage 5: aggregate + ReLU, wave per node.
        int blocks = (n_nodes * 64 + 255) / 256;
        if (use_bf16)
            aggregate_bf16_k<<<blocks, 256, 0, stream>>>(
                x_bf16, offsets, counts,
                reinterpret_cast<const long long*>(te_sorted), out, n_nodes);
        else
            aggregate_f32_k<<<blocks, 256, 0, stream>>>(
                x, offsets, counts, te_sorted, out, n_nodes);
    }
}